// Round 5
// baseline (287.861 us; speedup 1.0000x reference)
//
#include <hip/hip_runtime.h>

#define D      128
#define DM     64
#define DMLP   512
#define PMAX   150
#define VOC    152
#define EQT    151
#define NBATCH 65536

typedef __attribute__((ext_vector_type(8))) __bf16 bf16x8;
typedef __attribute__((ext_vector_type(4))) float  f32x4;

__device__ __forceinline__ float silu_f(float x){ return x / (1.0f + expf(-x)); }

// ---- workspace layout (float-slot offsets) ----
#define OFF_MEMVEC 0        // 150*128 f32
#define OFF_X3BASE 19200    // 128 f32
#define OFF_KE     19328    // 152*128 f32
#define OFF_KP     38784    // 4*128 f32
#define OFF_SC     39296    // 150*624 f32
#define OFF_O0     132896   // 150*512 bf16
#define OFF_O1     171296   // 150*512 bf16
#define OFF_O2     209696   // 150*512 bf16
#define OFF_O3     248096   // 512 bf16
#define OFF_M3B    248352   // 150*128 bf16
#define OFF_W1F    257952   // 65536 bf16 frag-packed
#define OFF_W2F    290720   // 65536 bf16
#define OFF_WUF    323488   // 20480 bf16

// ===== P1: token-side tables + O-tables + memvec + weight repack (832 blocks x 256)
__global__ void k_P1(const float* __restrict__ tok, const float* __restrict__ pos,
                     const float* __restrict__ W_mem, const float* __restrict__ b_mem,
                     const float* __restrict__ W_sur, const float* __restrict__ b_sur,
                     const float* __restrict__ W_m2r, const float* __restrict__ b_m2r,
                     const float* __restrict__ W_K, const float* __restrict__ W_V,
                     const float* __restrict__ W_O,
                     const float* __restrict__ W1, const float* __restrict__ W2,
                     const float* __restrict__ WU,
                     float* __restrict__ memvec, float* __restrict__ x3base,
                     float* __restrict__ KE, float* __restrict__ KP,
                     __bf16* __restrict__ O0, __bf16* __restrict__ O1,
                     __bf16* __restrict__ O2, __bf16* __restrict__ O3,
                     __bf16* __restrict__ W1f, __bf16* __restrict__ W2f, __bf16* __restrict__ WUf)
{
    int r = blockIdx.x, t = threadIdx.x;
    if (r < 150) {
        int p = r;
        __shared__ float sx0[D], sz[DM], sdiff[D], szu[DM];
        if (t < D) sx0[t] = tok[p*D + t] + pos[t];
        __syncthreads();
        if (t < DM) {
            float acc = b_mem[t];
            for (int d = 0; d < D; d++) acc += sx0[d] * W_mem[d*DM + t];
            sz[t] = silu_f(acc);
        }
        __syncthreads();
        if (t < D) {
            float acc = b_sur[t];
            for (int j = 0; j < DM; j++) acc += sz[j] * W_sur[j*D + t];
            sdiff[t] = sx0[t] - acc;
        }
        __syncthreads();
        if (t < DM) {
            float acc = 0.f;
            for (int d = 0; d < D; d++) acc += sdiff[d] * W_mem[d*DM + t];
            szu[t] = sz[t] + silu_f(acc);
        }
        __syncthreads();
        if (t < D) {
            float acc = b_m2r[t];
            for (int j = 0; j < DM; j++) acc += szu[j] * W_m2r[j*D + t];
            memvec[p*D + t] = acc;
        }
    } else if (r == 150) {
        if (t < D) x3base[t] = tok[EQT*D + t] + pos[3*D + t];
    } else if (r < 307) {
        int idx = r - 151;
        const float* src = (idx < 152) ? (tok + idx*D) : (pos + (idx-152)*D);
        float*       dst = (idx < 152) ? (KE + idx*D)  : (KP + (idx-152)*D);
        __shared__ float s[D];
        if (t < D) s[t] = src[t];
        __syncthreads();
        if (t < D) {
            int h = t >> 5, k = t & 31;
            float acc = 0.f;
            for (int d = 0; d < D; d++) acc += s[d] * W_K[h*4096 + d*32 + k];
            dst[t] = acc;
        }
    } else if (r < 758) {
        int idx = r - 307;
        int tt, v; __bf16* outp;
        if (idx < 150)      { tt = 0; v = idx;       outp = O0 + v*512; }
        else if (idx < 300) { tt = 1; v = idx - 150; outp = O1 + (idx-150)*512; }
        else if (idx < 450) { tt = 2; v = idx - 300; outp = O2 + (idx-300)*512; }
        else                { tt = 3; v = EQT;       outp = O3; }
        __shared__ float sTP[D], sv[D];
        if (t < D) sTP[t] = tok[v*D + t] + pos[tt*D + t];
        __syncthreads();
        if (t < D) {
            int h = t >> 5, k = t & 31;
            float acc = 0.f;
            for (int d = 0; d < D; d++) acc += sTP[d] * W_V[h*4096 + d*32 + k];
            sv[t] = acc;
        }
        __syncthreads();
        #pragma unroll
        for (int i = 0; i < 2; i++) {
            int c = t + i*256;
            int h = c >> 7, m = c & 127;
            float acc = 0.f;
            for (int k = 0; k < 32; k++) acc += sv[h*32 + k] * W_O[h*4096 + k*128 + m];
            outp[c] = (__bf16)acc;
        }
    } else if (r < 790) {
        int f = (r-758)*256 + t;                       // W1 128x512
        int l = f & 63, kb = (f>>6) & 3, nb = f >> 8;
        int k0 = kb*32 + (l>>4)*8, n = nb*16 + (l&15);
        #pragma unroll
        for (int j = 0; j < 8; j++) W1f[f*8 + j] = (__bf16)W1[(k0+j)*DMLP + n];
    } else if (r < 822) {
        int f = (r-790)*256 + t;                       // W2 512x128
        int l = f & 63, kb = (f>>6) & 15, nb = f >> 10;
        int k0 = kb*32 + (l>>4)*8, n = nb*16 + (l&15);
        #pragma unroll
        for (int j = 0; j < 8; j++) W2f[f*8 + j] = (__bf16)W2[(k0+j)*D + n];
    } else {
        int f = (r-822)*256 + t;                       // W_un 128x150 (N pad 160)
        int l = f & 63, kb = (f>>6) & 3, nb = f >> 8;
        int k0 = kb*32 + (l>>4)*8, n = nb*16 + (l&15);
        #pragma unroll
        for (int j = 0; j < 8; j++) WUf[f*8 + j] = (__bf16)((n < 150) ? WU[(k0+j)*150 + n] : 0.f);
    }
}

// ===== P2: per-p tables — Q3 (inline), SC score table, M3B (150 blocks x 256)
__global__ void k_P2(const float* __restrict__ memvec, const float* __restrict__ x3base,
                     const float* __restrict__ W_Q, const float* __restrict__ W_V,
                     const float* __restrict__ W_O,
                     const float* __restrict__ KE, const float* __restrict__ KP,
                     float* __restrict__ SC, __bf16* __restrict__ M3B)
{
    int p = blockIdx.x, t = threadIdx.x;
    __shared__ float sMem[D], sIn[D], sQ3[D], sMV[D];
    if (t < D) { float m = memvec[p*D + t]; sMem[t] = m; sIn[t] = m + x3base[t]; }
    __syncthreads();
    if (t < D) {
        int h = t >> 5, k = t & 31;
        float acc = 0.f;
        for (int d = 0; d < D; d++) acc += sIn[d] * W_Q[h*4096 + d*32 + k];
        sQ3[t] = acc;
    } else {
        int c = t - D; int h = c >> 5, k = c & 31;
        float acc = 0.f;
        for (int d = 0; d < D; d++) acc += sMem[d] * W_V[h*4096 + d*32 + k];
        sMV[c] = acc;
    }
    __syncthreads();
    const float scale = 0.17677669529663687f;
    for (int i = t; i < 624; i += 256) {
        int v = i >> 2, h = i & 3;
        const float* qh = sQ3 + h*32;
        float acc = 0.f;
        if (v < 152) {
            const float* ke = KE + v*D + h*32;
            for (int k = 0; k < 32; k++) acc += qh[k] * ke[k];
        } else if (v == 152) {
            const float* ke = KE + p*D + h*32; const float* kp = KP + h*32;
            for (int k = 0; k < 32; k++) acc += qh[k] * (ke[k] + kp[k]);
        } else if (v == 153) {
            const float* ke = KE + EQT*D + h*32; const float* kp = KP + 3*D + h*32;
            for (int k = 0; k < 32; k++) acc += qh[k] * (ke[k] + kp[k]);
        } else if (v == 154) {
            const float* kp = KP + 1*D + h*32;
            for (int k = 0; k < 32; k++) acc += qh[k] * kp[k];
        } else {
            const float* kp = KP + 2*D + h*32;
            for (int k = 0; k < 32; k++) acc += qh[k] * kp[k];
        }
        SC[p*624 + i] = acc * scale;
    }
    if (t < D) {
        float acc = sIn[t];
        for (int c = 0; c < D; c++) acc += sMV[c] * W_O[c*D + t];
        M3B[p*D + t] = (__bf16)acc;
    }
}

// ===== main: 512 blocks x 256, 128 samples, ONE barrier, weights streamed ===
// LDS: [0,32768) region A — x3 frags (8 tiles), then per-wave 8 KB spans reused
//      as wave-private H panels; [32768, 35968) biases.
__global__ __launch_bounds__(256, 4) void k_mainN(
    const int* __restrict__ p_val, const int* __restrict__ a_tok, const int* __restrict__ b_tok,
    const float* __restrict__ SC, const __bf16* __restrict__ O0, const __bf16* __restrict__ O1,
    const __bf16* __restrict__ O2, const __bf16* __restrict__ O3g, const __bf16* __restrict__ M3B,
    const __bf16* __restrict__ W1f, const __bf16* __restrict__ W2f, const __bf16* __restrict__ WUf,
    const float* __restrict__ b1, const float* __restrict__ b2, const float* __restrict__ bun,
    float* __restrict__ out)
{
    __shared__ __align__(16) char smem[35968];
    char*  sA = smem;
    float* sB = (float*)(smem + 32768);

    int tid = threadIdx.x;
    int gbase = blockIdx.x * 128;
    int wv = tid >> 6, l = tid & 63, lr = l & 15, quad = l >> 4;

    // stage biases (covered by the single barrier below)
    for (int i = tid; i < 512; i += 256) sB[i] = b1[i];
    if (tid < 128) sB[512 + tid] = b2[tid];
    if (tid < 160) sB[640 + tid] = bun[tid];

    // ---------------- phase 1a: scores + softmax (thread = sample, 2 heads) --
    int s = tid >> 1, half = tid & 1;
    int gs = gbase + s;
    int p = p_val[gs], ta = a_tok[gs], tb = b_tok[gs];
    float wloc[8];
    {
        const float* SCp = SC + p*624;
        #pragma unroll
        for (int hh = 0; hh < 2; hh++) {
            int h = half*2 + hh;
            float sc0 = SCp[608 + h];
            float sc3 = SCp[612 + h];
            float sc1 = SCp[ta*4 + h] + SCp[616 + h];
            float sc2 = SCp[tb*4 + h] + SCp[620 + h];
            float mx = fmaxf(fmaxf(sc0, sc1), fmaxf(sc2, sc3));
            float e0 = expf(sc0-mx), e1 = expf(sc1-mx), e2 = expf(sc2-mx), e3 = expf(sc3-mx);
            float inv = 1.f / (e0 + e1 + e2 + e3);
            wloc[hh*4+0] = e0*inv; wloc[hh*4+1] = e1*inv;
            wloc[hh*4+2] = e2*inv; wloc[hh*4+3] = e3*inv;
        }
    }
    // exchange with partner lane (tid^1 shares the sample) — no LDS, no barrier
    float w[16];
    #pragma unroll
    for (int j = 0; j < 8; j++) {
        float o = __shfl_xor(wloc[j], 1);
        if (half == 0) { w[j] = wloc[j]; w[8+j] = o; }
        else           { w[j] = o;       w[8+j] = wloc[j]; }
    }

    // ---------------- phase 1b: x3 -> A-fragment layout in region A ----------
    {
        const bf16x8* m3v = (const bf16x8*)(M3B + p*128);
        const bf16x8* t0  = (const bf16x8*)(O0 + p*512);
        const bf16x8* t1  = (const bf16x8*)(O1 + ta*512);
        const bf16x8* t2  = (const bf16x8*)(O2 + tb*512);
        const bf16x8* t3  = (const bf16x8*)O3g;
        int tile = s >> 4, slr = s & 15;
        #pragma unroll
        for (int jj = 0; jj < 8; jj++) {
            int c8 = half*8 + jj;
            bf16x8 mv = m3v[c8];
            float v[8];
            #pragma unroll
            for (int e = 0; e < 8; e++) v[e] = (float)mv[e];
            #pragma unroll
            for (int h = 0; h < 4; h++) {
                int o8 = h*16 + c8;
                bf16x8 e0 = t0[o8], e1 = t1[o8], e2 = t2[o8], e3 = t3[o8];
                float w0 = w[h*4+0], w1 = w[h*4+1], w2 = w[h*4+2], w3 = w[h*4+3];
                #pragma unroll
                for (int e = 0; e < 8; e++)
                    v[e] += w0*(float)e0[e] + w1*(float)e1[e] + w2*(float)e2[e] + w3*(float)e3[e];
            }
            bf16x8 st;
            #pragma unroll
            for (int e = 0; e < 8; e++) st[e] = (__bf16)v[e];
            int kb = c8 >> 2, q = c8 & 3;
            *(bf16x8*)(sA + (((tile*4 + kb)*64) + q*16 + slr)*16) = st;
        }
    }
    __syncthreads();   // the ONLY barrier

    // ---------------- load A-fragments; wave's 8 KB span becomes private -----
    bf16x8 a[2][4];
    #pragma unroll
    for (int t = 0; t < 2; t++)
        #pragma unroll
        for (int kb = 0; kb < 4; kb++)
            a[t][kb] = *(const bf16x8*)(sA + (((wv*2 + t)*4 + kb)*64 + l)*16);

    char* sHw = sA + wv*8192;          // wave-private from here on
    const bf16x8* W1v = (const bf16x8*)W1f;
    const bf16x8* W2v = (const bf16x8*)W2f;
    const bf16x8* WUv = (const bf16x8*)WUf;

    f32x4 acc2[2][8];
    #pragma unroll
    for (int t = 0; t < 2; t++)
        #pragma unroll
        for (int i = 0; i < 8; i++) acc2[t][i] = (f32x4){0.f, 0.f, 0.f, 0.f};

    // ---------------- MLP: 8 chunks of 64 hidden, barrier-free ---------------
    #pragma unroll
    for (int cc = 0; cc < 8; cc++) {
        #pragma unroll
        for (int nbl = 0; nbl < 4; nbl++) {
            int nbg = cc*4 + nbl;
            float bv = sB[nbg*16 + lr];
            bf16x8 w1[4];
            #pragma unroll
            for (int kb = 0; kb < 4; kb++)
                w1[kb] = W1v[(nbg*4 + kb)*64 + l];
            #pragma unroll
            for (int t = 0; t < 2; t++) {
                f32x4 acc = (f32x4){bv, bv, bv, bv};
                #pragma unroll
                for (int kb = 0; kb < 4; kb++)
                    acc = __builtin_amdgcn_mfma_f32_16x16x32_bf16(a[t][kb], w1[kb], acc, 0, 0, 0);
                char* base = sHw + t*2304;
                #pragma unroll
                for (int r = 0; r < 4; r++)
                    *(__bf16*)(base + (((quad*4 + r)*72) + nbl*16 + lr)*2) = (__bf16)fmaxf(acc[r], 0.f);
            }
        }
        #pragma unroll
        for (int kb2 = 0; kb2 < 2; kb2++) {
            bf16x8 h0 = *(const bf16x8*)(sHw +        (lr*72 + kb2*32 + quad*8)*2);
            bf16x8 h1 = *(const bf16x8*)(sHw + 2304 + (lr*72 + kb2*32 + quad*8)*2);
            #pragma unroll
            for (int nb2 = 0; nb2 < 8; nb2++) {
                bf16x8 w2 = W2v[(nb2*16 + cc*2 + kb2)*64 + l];
                acc2[0][nb2] = __builtin_amdgcn_mfma_f32_16x16x32_bf16(h0, w2, acc2[0][nb2], 0, 0, 0);
                acc2[1][nb2] = __builtin_amdgcn_mfma_f32_16x16x32_bf16(h1, w2, acc2[1][nb2], 0, 0, 0);
            }
        }
    }

    // ---------------- residual via identity-matrix MFMA ----------------------
    #pragma unroll
    for (int nb2 = 0; nb2 < 8; nb2++) {
        int kb = nb2 >> 1;
        bf16x8 bi;
        #pragma unroll
        for (int j = 0; j < 8; j++)
            bi[j] = (kb*32 + quad*8 + j == nb2*16 + lr) ? (__bf16)1.0f : (__bf16)0.0f;
        acc2[0][nb2] = __builtin_amdgcn_mfma_f32_16x16x32_bf16(a[0][kb], bi, acc2[0][nb2], 0, 0, 0);
        acc2[1][nb2] = __builtin_amdgcn_mfma_f32_16x16x32_bf16(a[1][kb], bi, acc2[1][nb2], 0, 0, 0);
    }

    // ---------------- epilogue + unembed, per tile (wave-private) ------------
    #pragma unroll
    for (int t = 0; t < 2; t++) {
        #pragma unroll
        for (int nb2 = 0; nb2 < 8; nb2++) {
            int n = nb2*16 + lr;
            float bv = sB[512 + n];
            char* base = sHw + (nb2 >> 2)*2304;
            #pragma unroll
            for (int r = 0; r < 4; r++) {
                float v = acc2[t][nb2][r] + bv;
                *(__bf16*)(base + (((quad*4 + r)*72) + (nb2 & 3)*16 + lr)*2) = (__bf16)v;
            }
        }
        bf16x8 au[4];
        #pragma unroll
        for (int kb = 0; kb < 4; kb++)
            au[kb] = *(const bf16x8*)(sHw + (kb >> 1)*2304 + (lr*72 + (kb & 1)*32 + quad*8)*2);
        #pragma unroll
        for (int nt = 0; nt < 10; nt++) {
            int n = nt*16 + lr;
            float bv = (n < 150) ? sB[640 + n] : 0.f;
            f32x4 acc = (f32x4){bv, bv, bv, bv};
            #pragma unroll
            for (int kb = 0; kb < 4; kb++) {
                bf16x8 wu = WUv[(nt*4 + kb)*64 + l];
                acc = __builtin_amdgcn_mfma_f32_16x16x32_bf16(au[kb], wu, acc, 0, 0, 0);
            }
            if (n < 150) {
                #pragma unroll
                for (int r = 0; r < 4; r++) {
                    int rowg = gbase + (wv*2 + t)*16 + quad*4 + r;
                    out[rowg*150 + n] = acc[r];
                }
            }
        }
    }
}

// ============================ launcher ======================================
extern "C" void kernel_launch(void* const* d_in, const int* in_sizes, int n_in,
                              void* d_out, int out_size, void* d_ws, size_t ws_size,
                              hipStream_t stream) {
    const int*   p_val = (const int*)d_in[0];
    const int*   a_tok = (const int*)d_in[1];
    const int*   b_tok = (const int*)d_in[2];
    const float* tok   = (const float*)d_in[3];
    const float* pos   = (const float*)d_in[4];
    const float* W_mem = (const float*)d_in[5];
    const float* b_mem = (const float*)d_in[6];
    const float* W_sur = (const float*)d_in[7];
    const float* b_sur = (const float*)d_in[8];
    const float* W_m2r = (const float*)d_in[9];
    const float* b_m2r = (const float*)d_in[10];
    const float* W_Q   = (const float*)d_in[11];
    const float* W_K   = (const float*)d_in[12];
    const float* W_V   = (const float*)d_in[13];
    const float* W_O   = (const float*)d_in[14];
    const float* W1    = (const float*)d_in[15];
    const float* b1    = (const float*)d_in[16];
    const float* W2    = (const float*)d_in[17];
    const float* b2    = (const float*)d_in[18];
    const float* WU    = (const float*)d_in[19];
    const float* bun   = (const float*)d_in[20];
    float* out = (float*)d_out;

    float* ws = (float*)d_ws;
    float* memvec = ws + OFF_MEMVEC;
    float* x3base = ws + OFF_X3BASE;
    float* KE     = ws + OFF_KE;
    float* KP     = ws + OFF_KP;
    float* SC     = ws + OFF_SC;
    __bf16* O0    = (__bf16*)(ws + OFF_O0);
    __bf16* O1    = (__bf16*)(ws + OFF_O1);
    __bf16* O2    = (__bf16*)(ws + OFF_O2);
    __bf16* O3    = (__bf16*)(ws + OFF_O3);
    __bf16* M3B   = (__bf16*)(ws + OFF_M3B);
    __bf16* W1f   = (__bf16*)(ws + OFF_W1F);
    __bf16* W2f   = (__bf16*)(ws + OFF_W2F);
    __bf16* WUf   = (__bf16*)(ws + OFF_WUF);

    k_P1<<<832, 256, 0, stream>>>(tok, pos, W_mem, b_mem, W_sur, b_sur, W_m2r, b_m2r,
                                  W_K, W_V, W_O, W1, W2, WU,
                                  memvec, x3base, KE, KP, O0, O1, O2, O3, W1f, W2f, WUf);
    k_P2<<<150, 256, 0, stream>>>(memvec, x3base, W_Q, W_V, W_O, KE, KP, SC, M3B);
    k_mainN<<<NBATCH/128, 256, 0, stream>>>(p_val, a_tok, b_tok, SC, O0, O1, O2, O3, M3B,
                                            W1f, W2f, WUf, b1, b2, bun, out);
}

// Round 6
// 216.179 us; speedup vs baseline: 1.3316x; 1.3316x over previous
//
#include <hip/hip_runtime.h>

#define D      128
#define DM     64
#define DMLP   512
#define PMAX   150
#define VOC    152
#define EQT    151
#define NBATCH 65536

typedef __attribute__((ext_vector_type(8))) __bf16 bf16x8;
typedef __attribute__((ext_vector_type(4))) float  f32x4;

__device__ __forceinline__ float silu_f(float x){ return x / (1.0f + expf(-x)); }

// ---- workspace layout (float-slot offsets) ----
#define OFF_MEMVEC 0        // 150*128 f32
#define OFF_X3BASE 19200    // 128 f32
#define OFF_KE     19328    // 152*128 f32
#define OFF_KP     38784    // 4*128 f32
#define OFF_SC     39296    // 150*624 f32
#define OFF_O0     132896   // 150*512 bf16
#define OFF_O1     171296   // 150*512 bf16
#define OFF_O2     209696   // 150*512 bf16
#define OFF_O3     248096   // 512 bf16
#define OFF_M3B    248352   // 150*128 bf16
#define OFF_W1F    257952   // 65536 bf16 frag-packed
#define OFF_W2F    290720   // 65536 bf16
#define OFF_WUF    323488   // 20480 bf16

// ===== P1: token-side tables + O-tables + memvec + weight repack (832 blocks x 256)
__global__ void k_P1(const float* __restrict__ tok, const float* __restrict__ pos,
                     const float* __restrict__ W_mem, const float* __restrict__ b_mem,
                     const float* __restrict__ W_sur, const float* __restrict__ b_sur,
                     const float* __restrict__ W_m2r, const float* __restrict__ b_m2r,
                     const float* __restrict__ W_K, const float* __restrict__ W_V,
                     const float* __restrict__ W_O,
                     const float* __restrict__ W1, const float* __restrict__ W2,
                     const float* __restrict__ WU,
                     float* __restrict__ memvec, float* __restrict__ x3base,
                     float* __restrict__ KE, float* __restrict__ KP,
                     __bf16* __restrict__ O0, __bf16* __restrict__ O1,
                     __bf16* __restrict__ O2, __bf16* __restrict__ O3,
                     __bf16* __restrict__ W1f, __bf16* __restrict__ W2f, __bf16* __restrict__ WUf)
{
    int r = blockIdx.x, t = threadIdx.x;
    if (r < 150) {
        int p = r;
        __shared__ float sx0[D], sz[DM], sdiff[D], szu[DM];
        if (t < D) sx0[t] = tok[p*D + t] + pos[t];
        __syncthreads();
        if (t < DM) {
            float acc = b_mem[t];
            for (int d = 0; d < D; d++) acc += sx0[d] * W_mem[d*DM + t];
            sz[t] = silu_f(acc);
        }
        __syncthreads();
        if (t < D) {
            float acc = b_sur[t];
            for (int j = 0; j < DM; j++) acc += sz[j] * W_sur[j*D + t];
            sdiff[t] = sx0[t] - acc;
        }
        __syncthreads();
        if (t < DM) {
            float acc = 0.f;
            for (int d = 0; d < D; d++) acc += sdiff[d] * W_mem[d*DM + t];
            szu[t] = sz[t] + silu_f(acc);
        }
        __syncthreads();
        if (t < D) {
            float acc = b_m2r[t];
            for (int j = 0; j < DM; j++) acc += szu[j] * W_m2r[j*D + t];
            memvec[p*D + t] = acc;
        }
    } else if (r == 150) {
        if (t < D) x3base[t] = tok[EQT*D + t] + pos[3*D + t];
    } else if (r < 307) {
        int idx = r - 151;
        const float* src = (idx < 152) ? (tok + idx*D) : (pos + (idx-152)*D);
        float*       dst = (idx < 152) ? (KE + idx*D)  : (KP + (idx-152)*D);
        __shared__ float s[D];
        if (t < D) s[t] = src[t];
        __syncthreads();
        if (t < D) {
            int h = t >> 5, k = t & 31;
            float acc = 0.f;
            for (int d = 0; d < D; d++) acc += s[d] * W_K[h*4096 + d*32 + k];
            dst[t] = acc;
        }
    } else if (r < 758) {
        int idx = r - 307;
        int tt, v; __bf16* outp;
        if (idx < 150)      { tt = 0; v = idx;       outp = O0 + v*512; }
        else if (idx < 300) { tt = 1; v = idx - 150; outp = O1 + (idx-150)*512; }
        else if (idx < 450) { tt = 2; v = idx - 300; outp = O2 + (idx-300)*512; }
        else                { tt = 3; v = EQT;       outp = O3; }
        __shared__ float sTP[D], sv[D];
        if (t < D) sTP[t] = tok[v*D + t] + pos[tt*D + t];
        __syncthreads();
        if (t < D) {
            int h = t >> 5, k = t & 31;
            float acc = 0.f;
            for (int d = 0; d < D; d++) acc += sTP[d] * W_V[h*4096 + d*32 + k];
            sv[t] = acc;
        }
        __syncthreads();
        #pragma unroll
        for (int i = 0; i < 2; i++) {
            int c = t + i*256;
            int h = c >> 7, m = c & 127;
            float acc = 0.f;
            for (int k = 0; k < 32; k++) acc += sv[h*32 + k] * W_O[h*4096 + k*128 + m];
            outp[c] = (__bf16)acc;
        }
    } else if (r < 790) {
        int f = (r-758)*256 + t;                       // W1 128x512
        int l = f & 63, kb = (f>>6) & 3, nb = f >> 8;
        int k0 = kb*32 + (l>>4)*8, n = nb*16 + (l&15);
        #pragma unroll
        for (int j = 0; j < 8; j++) W1f[f*8 + j] = (__bf16)W1[(k0+j)*DMLP + n];
    } else if (r < 822) {
        int f = (r-790)*256 + t;                       // W2 512x128
        int l = f & 63, kb = (f>>6) & 15, nb = f >> 10;
        int k0 = kb*32 + (l>>4)*8, n = nb*16 + (l&15);
        #pragma unroll
        for (int j = 0; j < 8; j++) W2f[f*8 + j] = (__bf16)W2[(k0+j)*D + n];
    } else {
        int f = (r-822)*256 + t;                       // W_un 128x150 (N pad 160)
        int l = f & 63, kb = (f>>6) & 3, nb = f >> 8;
        int k0 = kb*32 + (l>>4)*8, n = nb*16 + (l&15);
        #pragma unroll
        for (int j = 0; j < 8; j++) WUf[f*8 + j] = (__bf16)((n < 150) ? WU[(k0+j)*150 + n] : 0.f);
    }
}

// ===== P2: per-p tables — Q3 (inline), SC score table, M3B (150 blocks x 256)
__global__ void k_P2(const float* __restrict__ memvec, const float* __restrict__ x3base,
                     const float* __restrict__ W_Q, const float* __restrict__ W_V,
                     const float* __restrict__ W_O,
                     const float* __restrict__ KE, const float* __restrict__ KP,
                     float* __restrict__ SC, __bf16* __restrict__ M3B)
{
    int p = blockIdx.x, t = threadIdx.x;
    __shared__ float sMem[D], sIn[D], sQ3[D], sMV[D];
    if (t < D) { float m = memvec[p*D + t]; sMem[t] = m; sIn[t] = m + x3base[t]; }
    __syncthreads();
    if (t < D) {
        int h = t >> 5, k = t & 31;
        float acc = 0.f;
        for (int d = 0; d < D; d++) acc += sIn[d] * W_Q[h*4096 + d*32 + k];
        sQ3[t] = acc;
    } else {
        int c = t - D; int h = c >> 5, k = c & 31;
        float acc = 0.f;
        for (int d = 0; d < D; d++) acc += sMem[d] * W_V[h*4096 + d*32 + k];
        sMV[c] = acc;
    }
    __syncthreads();
    const float scale = 0.17677669529663687f;
    for (int i = t; i < 624; i += 256) {
        int v = i >> 2, h = i & 3;
        const float* qh = sQ3 + h*32;
        float acc = 0.f;
        if (v < 152) {
            const float* ke = KE + v*D + h*32;
            for (int k = 0; k < 32; k++) acc += qh[k] * ke[k];
        } else if (v == 152) {
            const float* ke = KE + p*D + h*32; const float* kp = KP + h*32;
            for (int k = 0; k < 32; k++) acc += qh[k] * (ke[k] + kp[k]);
        } else if (v == 153) {
            const float* ke = KE + EQT*D + h*32; const float* kp = KP + 3*D + h*32;
            for (int k = 0; k < 32; k++) acc += qh[k] * (ke[k] + kp[k]);
        } else if (v == 154) {
            const float* kp = KP + 1*D + h*32;
            for (int k = 0; k < 32; k++) acc += qh[k] * kp[k];
        } else {
            const float* kp = KP + 2*D + h*32;
            for (int k = 0; k < 32; k++) acc += qh[k] * kp[k];
        }
        SC[p*624 + i] = acc * scale;
    }
    if (t < D) {
        float acc = sIn[t];
        for (int c = 0; c < D; c++) acc += sMV[c] * W_O[c*D + t];
        M3B[p*D + t] = (__bf16)acc;
    }
}

// ===== main: 1024 blocks x 256, 64 samples, 1 tile/wave, one barrier ========
// LDS: [0,16384) x3 frags (4 waves x 4 kb x 64 x 16B)
//      [16384,34816) 4 x 4608B wave-private H panels
//      [34816,38016) biases (b1 512, b2 128, bun 160)
__global__ __launch_bounds__(256, 3) void k_mainP(
    const int* __restrict__ p_val, const int* __restrict__ a_tok, const int* __restrict__ b_tok,
    const float* __restrict__ SC, const __bf16* __restrict__ O0, const __bf16* __restrict__ O1,
    const __bf16* __restrict__ O2, const __bf16* __restrict__ O3g, const __bf16* __restrict__ M3B,
    const __bf16* __restrict__ W1f, const __bf16* __restrict__ W2f, const __bf16* __restrict__ WUf,
    const float* __restrict__ b1, const float* __restrict__ b2, const float* __restrict__ bun,
    float* __restrict__ out)
{
    __shared__ __align__(16) char smem[38016];
    char*  sX = smem;
    float* sB = (float*)(smem + 34816);

    int tid = threadIdx.x;
    int gbase = blockIdx.x * 64;
    int wv = tid >> 6, l = tid & 63, lr = l & 15, quad = l >> 4;

    // stage biases (cross-wave; covered by the single barrier)
    for (int i = tid; i < 512; i += 256) sB[i] = b1[i];
    if (tid < 128) sB[512 + tid] = b2[tid];
    if (tid < 160) sB[640 + tid] = bun[tid];

    // ---------------- phase 1a: scores + softmax (thread = (sample, head)) ---
    int s = tid >> 2, h = tid & 3;
    int gs = gbase + s;
    int p = p_val[gs], ta = a_tok[gs], tb = b_tok[gs];
    float wloc[4];
    {
        const float* SCp = SC + p*624;
        float sc0 = SCp[608 + h];
        float sc3 = SCp[612 + h];
        float sc1 = SCp[ta*4 + h] + SCp[616 + h];
        float sc2 = SCp[tb*4 + h] + SCp[620 + h];
        float mx = fmaxf(fmaxf(sc0, sc1), fmaxf(sc2, sc3));
        float e0 = expf(sc0-mx), e1 = expf(sc1-mx), e2 = expf(sc2-mx), e3 = expf(sc3-mx);
        float inv = 1.f / (e0 + e1 + e2 + e3);
        wloc[0] = e0*inv; wloc[1] = e1*inv; wloc[2] = e2*inv; wloc[3] = e3*inv;
    }
    // gather all 16 weights for this sample via intra-group shuffles
    float w[16];
    #pragma unroll
    for (int j = 0; j < 4; j++) w[h*4 + j] = wloc[j];
    #pragma unroll
    for (int m = 1; m < 4; m++) {
        int oh = h ^ m;
        #pragma unroll
        for (int j = 0; j < 4; j++) w[oh*4 + j] = __shfl_xor(wloc[j], m);
    }

    // ---------------- phase 1b: x3 -> A-fragment layout (wave-private) -------
    {
        const bf16x8* m3v = (const bf16x8*)(M3B + p*128);
        const bf16x8* t0  = (const bf16x8*)(O0 + p*512);
        const bf16x8* t1  = (const bf16x8*)(O1 + ta*512);
        const bf16x8* t2  = (const bf16x8*)(O2 + tb*512);
        const bf16x8* t3  = (const bf16x8*)O3g;
        int slr = s & 15;
        #pragma unroll
        for (int jj = 0; jj < 4; jj++) {
            int c8 = h*4 + jj;                 // h doubles as col-quarter index
            bf16x8 mv = m3v[c8];
            float v[8];
            #pragma unroll
            for (int e = 0; e < 8; e++) v[e] = (float)mv[e];
            #pragma unroll
            for (int hh = 0; hh < 4; hh++) {
                int o8 = hh*16 + c8;
                bf16x8 e0 = t0[o8], e1 = t1[o8], e2 = t2[o8], e3 = t3[o8];
                float w0 = w[hh*4+0], w1 = w[hh*4+1], w2 = w[hh*4+2], w3 = w[hh*4+3];
                #pragma unroll
                for (int e = 0; e < 8; e++)
                    v[e] += w0*(float)e0[e] + w1*(float)e1[e] + w2*(float)e2[e] + w3*(float)e3[e];
            }
            bf16x8 st;
            #pragma unroll
            for (int e = 0; e < 8; e++) st[e] = (__bf16)v[e];
            // frag coords: kb = c8>>2 = h, qq = c8&3 = jj
            *(bf16x8*)(sX + (((wv*4 + h)*64) + jj*16 + slr)*16) = st;
        }
    }
    __syncthreads();   // the only barrier (biases + safety)

    // ---------------- load A-fragments; everything below is wave-private -----
    bf16x8 a[4];
    #pragma unroll
    for (int kb = 0; kb < 4; kb++)
        a[kb] = *(const bf16x8*)(sX + ((wv*4 + kb)*64 + l)*16);

    char* sHw = smem + 16384 + wv*4608;
    const bf16x8* W1v = (const bf16x8*)W1f;
    const bf16x8* W2v = (const bf16x8*)W2f;
    const bf16x8* WUv = (const bf16x8*)WUf;

    f32x4 acc2[8];
    #pragma unroll
    for (int i = 0; i < 8; i++) acc2[i] = (f32x4){0.f, 0.f, 0.f, 0.f};

    // ---------------- MLP: 8 chunks of 64 hidden, barrier-free ---------------
    #pragma unroll
    for (int cc = 0; cc < 8; cc++) {
        #pragma unroll
        for (int nbl = 0; nbl < 4; nbl++) {
            int nbg = cc*4 + nbl;
            float bv = sB[nbg*16 + lr];
            bf16x8 w1[4];
            #pragma unroll
            for (int kb = 0; kb < 4; kb++)
                w1[kb] = W1v[(nbg*4 + kb)*64 + l];
            f32x4 acc = (f32x4){bv, bv, bv, bv};
            #pragma unroll
            for (int kb = 0; kb < 4; kb++)
                acc = __builtin_amdgcn_mfma_f32_16x16x32_bf16(a[kb], w1[kb], acc, 0, 0, 0);
            #pragma unroll
            for (int r = 0; r < 4; r++)
                *(__bf16*)(sHw + (((quad*4 + r)*72) + nbl*16 + lr)*2) = (__bf16)fmaxf(acc[r], 0.f);
        }
        #pragma unroll
        for (int kb2 = 0; kb2 < 2; kb2++) {
            bf16x8 a2 = *(const bf16x8*)(sHw + (lr*72 + kb2*32 + quad*8)*2);
            #pragma unroll
            for (int nb2 = 0; nb2 < 8; nb2++) {
                bf16x8 w2 = W2v[(nb2*16 + cc*2 + kb2)*64 + l];
                acc2[nb2] = __builtin_amdgcn_mfma_f32_16x16x32_bf16(a2, w2, acc2[nb2], 0, 0, 0);
            }
        }
    }

    // ---------------- residual via identity-matrix MFMA ----------------------
    #pragma unroll
    for (int nb2 = 0; nb2 < 8; nb2++) {
        int kb = nb2 >> 1;
        bf16x8 bi;
        #pragma unroll
        for (int j = 0; j < 8; j++)
            bi[j] = (kb*32 + quad*8 + j == nb2*16 + lr) ? (__bf16)1.0f : (__bf16)0.0f;
        acc2[nb2] = __builtin_amdgcn_mfma_f32_16x16x32_bf16(a[kb], bi, acc2[nb2], 0, 0, 0);
    }

    // ---------------- epilogue: x'' -> 2 wave-private panels, then unembed ---
    #pragma unroll
    for (int nb2 = 0; nb2 < 8; nb2++) {
        int n = nb2*16 + lr;
        float bv = sB[512 + n];
        char* base = sHw + (nb2 >> 2)*2304;
        #pragma unroll
        for (int r = 0; r < 4; r++) {
            float v = acc2[nb2][r] + bv;
            *(__bf16*)(base + (((quad*4 + r)*72) + (nb2 & 3)*16 + lr)*2) = (__bf16)v;
        }
    }
    bf16x8 au[4];
    #pragma unroll
    for (int kb = 0; kb < 4; kb++)
        au[kb] = *(const bf16x8*)(sHw + (kb >> 1)*2304 + (lr*72 + (kb & 1)*32 + quad*8)*2);
    #pragma unroll
    for (int nt = 0; nt < 10; nt++) {
        int n = nt*16 + lr;
        float bv = (n < 150) ? sB[640 + n] : 0.f;
        f32x4 acc = (f32x4){bv, bv, bv, bv};
        #pragma unroll
        for (int kb = 0; kb < 4; kb++) {
            bf16x8 wu = WUv[(nt*4 + kb)*64 + l];
            acc = __builtin_amdgcn_mfma_f32_16x16x32_bf16(au[kb], wu, acc, 0, 0, 0);
        }
        if (n < 150) {
            #pragma unroll
            for (int r = 0; r < 4; r++) {
                int rowg = gbase + wv*16 + quad*4 + r;
                out[rowg*150 + n] = acc[r];
            }
        }
    }
}

// ============================ launcher ======================================
extern "C" void kernel_launch(void* const* d_in, const int* in_sizes, int n_in,
                              void* d_out, int out_size, void* d_ws, size_t ws_size,
                              hipStream_t stream) {
    const int*   p_val = (const int*)d_in[0];
    const int*   a_tok = (const int*)d_in[1];
    const int*   b_tok = (const int*)d_in[2];
    const float* tok   = (const float*)d_in[3];
    const float* pos   = (const float*)d_in[4];
    const float* W_mem = (const float*)d_in[5];
    const float* b_mem = (const float*)d_in[6];
    const float* W_sur = (const float*)d_in[7];
    const float* b_sur = (const float*)d_in[8];
    const float* W_m2r = (const float*)d_in[9];
    const float* b_m2r = (const float*)d_in[10];
    const float* W_Q   = (const float*)d_in[11];
    const float* W_K   = (const float*)d_in[12];
    const float* W_V   = (const float*)d_in[13];
    const float* W_O   = (const float*)d_in[14];
    const float* W1    = (const float*)d_in[15];
    const float* b1    = (const float*)d_in[16];
    const float* W2    = (const float*)d_in[17];
    const float* b2    = (const float*)d_in[18];
    const float* WU    = (const float*)d_in[19];
    const float* bun   = (const float*)d_in[20];
    float* out = (float*)d_out;

    float* ws = (float*)d_ws;
    float* memvec = ws + OFF_MEMVEC;
    float* x3base = ws + OFF_X3BASE;
    float* KE     = ws + OFF_KE;
    float* KP     = ws + OFF_KP;
    float* SC     = ws + OFF_SC;
    __bf16* O0    = (__bf16*)(ws + OFF_O0);
    __bf16* O1    = (__bf16*)(ws + OFF_O1);
    __bf16* O2    = (__bf16*)(ws + OFF_O2);
    __bf16* O3    = (__bf16*)(ws + OFF_O3);
    __bf16* M3B   = (__bf16*)(ws + OFF_M3B);
    __bf16* W1f   = (__bf16*)(ws + OFF_W1F);
    __bf16* W2f   = (__bf16*)(ws + OFF_W2F);
    __bf16* WUf   = (__bf16*)(ws + OFF_WUF);

    k_P1<<<832, 256, 0, stream>>>(tok, pos, W_mem, b_mem, W_sur, b_sur, W_m2r, b_m2r,
                                  W_K, W_V, W_O, W1, W2, WU,
                                  memvec, x3base, KE, KP, O0, O1, O2, O3, W1f, W2f, WUf);
    k_P2<<<150, 256, 0, stream>>>(memvec, x3base, W_Q, W_V, W_O, KE, KP, SC, M3B);
    k_mainP<<<NBATCH/64, 256, 0, stream>>>(p_val, a_tok, b_tok, SC, O0, O1, O2, O3, M3B,
                                           W1f, W2f, WUf, b1, b2, bun, out);
}

// Round 7
// 212.691 us; speedup vs baseline: 1.3534x; 1.0164x over previous
//
#include <hip/hip_runtime.h>

#define D      128
#define DM     64
#define DMLP   512
#define PMAX   150
#define VOC    152
#define EQT    151
#define NBATCH 65536

typedef __attribute__((ext_vector_type(8))) __bf16 bf16x8;
typedef __attribute__((ext_vector_type(4))) float  f32x4;

__device__ __forceinline__ float silu_f(float x){ return x / (1.0f + expf(-x)); }

// ---- workspace layout (float-slot offsets) ----
#define OFF_MEMVEC 0        // 150*128 f32
#define OFF_X3BASE 19200    // 128 f32
#define OFF_KE     19328    // 152*128 f32
#define OFF_KP     38784    // 4*128 f32
#define OFF_SC     39296    // 150*624 f32
#define OFF_O0     132896   // 150*512 bf16
#define OFF_O1     171296   // 150*512 bf16
#define OFF_O2     209696   // 150*512 bf16
#define OFF_O3     248096   // 512 bf16
#define OFF_M3B    248352   // 150*128 bf16
#define OFF_W1F    257952   // 65536 bf16 frag-packed
#define OFF_W2F    290720   // 65536 bf16
#define OFF_WUF    323488   // 20480 bf16
#define OFF_X3G    333728   // 65536*128 bf16 row-major x3

// ===== P1: token-side tables + O-tables + memvec + weight repack (832 blocks x 256)
__global__ void k_P1(const float* __restrict__ tok, const float* __restrict__ pos,
                     const float* __restrict__ W_mem, const float* __restrict__ b_mem,
                     const float* __restrict__ W_sur, const float* __restrict__ b_sur,
                     const float* __restrict__ W_m2r, const float* __restrict__ b_m2r,
                     const float* __restrict__ W_K, const float* __restrict__ W_V,
                     const float* __restrict__ W_O,
                     const float* __restrict__ W1, const float* __restrict__ W2,
                     const float* __restrict__ WU,
                     float* __restrict__ memvec, float* __restrict__ x3base,
                     float* __restrict__ KE, float* __restrict__ KP,
                     __bf16* __restrict__ O0, __bf16* __restrict__ O1,
                     __bf16* __restrict__ O2, __bf16* __restrict__ O3,
                     __bf16* __restrict__ W1f, __bf16* __restrict__ W2f, __bf16* __restrict__ WUf)
{
    int r = blockIdx.x, t = threadIdx.x;
    if (r < 150) {
        int p = r;
        __shared__ float sx0[D], sz[DM], sdiff[D], szu[DM];
        if (t < D) sx0[t] = tok[p*D + t] + pos[t];
        __syncthreads();
        if (t < DM) {
            float acc = b_mem[t];
            for (int d = 0; d < D; d++) acc += sx0[d] * W_mem[d*DM + t];
            sz[t] = silu_f(acc);
        }
        __syncthreads();
        if (t < D) {
            float acc = b_sur[t];
            for (int j = 0; j < DM; j++) acc += sz[j] * W_sur[j*D + t];
            sdiff[t] = sx0[t] - acc;
        }
        __syncthreads();
        if (t < DM) {
            float acc = 0.f;
            for (int d = 0; d < D; d++) acc += sdiff[d] * W_mem[d*DM + t];
            szu[t] = sz[t] + silu_f(acc);
        }
        __syncthreads();
        if (t < D) {
            float acc = b_m2r[t];
            for (int j = 0; j < DM; j++) acc += szu[j] * W_m2r[j*D + t];
            memvec[p*D + t] = acc;
        }
    } else if (r == 150) {
        if (t < D) x3base[t] = tok[EQT*D + t] + pos[3*D + t];
    } else if (r < 307) {
        int idx = r - 151;
        const float* src = (idx < 152) ? (tok + idx*D) : (pos + (idx-152)*D);
        float*       dst = (idx < 152) ? (KE + idx*D)  : (KP + (idx-152)*D);
        __shared__ float s[D];
        if (t < D) s[t] = src[t];
        __syncthreads();
        if (t < D) {
            int h = t >> 5, k = t & 31;
            float acc = 0.f;
            for (int d = 0; d < D; d++) acc += s[d] * W_K[h*4096 + d*32 + k];
            dst[t] = acc;
        }
    } else if (r < 758) {
        int idx = r - 307;
        int tt, v; __bf16* outp;
        if (idx < 150)      { tt = 0; v = idx;       outp = O0 + v*512; }
        else if (idx < 300) { tt = 1; v = idx - 150; outp = O1 + (idx-150)*512; }
        else if (idx < 450) { tt = 2; v = idx - 300; outp = O2 + (idx-300)*512; }
        else                { tt = 3; v = EQT;       outp = O3; }
        __shared__ float sTP[D], sv[D];
        if (t < D) sTP[t] = tok[v*D + t] + pos[tt*D + t];
        __syncthreads();
        if (t < D) {
            int h = t >> 5, k = t & 31;
            float acc = 0.f;
            for (int d = 0; d < D; d++) acc += sTP[d] * W_V[h*4096 + d*32 + k];
            sv[t] = acc;
        }
        __syncthreads();
        #pragma unroll
        for (int i = 0; i < 2; i++) {
            int c = t + i*256;
            int h = c >> 7, m = c & 127;
            float acc = 0.f;
            for (int k = 0; k < 32; k++) acc += sv[h*32 + k] * W_O[h*4096 + k*128 + m];
            outp[c] = (__bf16)acc;
        }
    } else if (r < 790) {
        int f = (r-758)*256 + t;                       // W1 128x512
        int l = f & 63, kb = (f>>6) & 3, nb = f >> 8;
        int k0 = kb*32 + (l>>4)*8, n = nb*16 + (l&15);
        #pragma unroll
        for (int j = 0; j < 8; j++) W1f[f*8 + j] = (__bf16)W1[(k0+j)*DMLP + n];
    } else if (r < 822) {
        int f = (r-790)*256 + t;                       // W2 512x128
        int l = f & 63, kb = (f>>6) & 15, nb = f >> 10;
        int k0 = kb*32 + (l>>4)*8, n = nb*16 + (l&15);
        #pragma unroll
        for (int j = 0; j < 8; j++) W2f[f*8 + j] = (__bf16)W2[(k0+j)*D + n];
    } else {
        int f = (r-822)*256 + t;                       // W_un 128x150 (N pad 160)
        int l = f & 63, kb = (f>>6) & 3, nb = f >> 8;
        int k0 = kb*32 + (l>>4)*8, n = nb*16 + (l&15);
        #pragma unroll
        for (int j = 0; j < 8; j++) WUf[f*8 + j] = (__bf16)((n < 150) ? WU[(k0+j)*150 + n] : 0.f);
    }
}

// ===== P2: per-p tables — Q3 (inline), SC score table, M3B (150 blocks x 256)
__global__ void k_P2(const float* __restrict__ memvec, const float* __restrict__ x3base,
                     const float* __restrict__ W_Q, const float* __restrict__ W_V,
                     const float* __restrict__ W_O,
                     const float* __restrict__ KE, const float* __restrict__ KP,
                     float* __restrict__ SC, __bf16* __restrict__ M3B)
{
    int p = blockIdx.x, t = threadIdx.x;
    __shared__ float sMem[D], sIn[D], sQ3[D], sMV[D];
    if (t < D) { float m = memvec[p*D + t]; sMem[t] = m; sIn[t] = m + x3base[t]; }
    __syncthreads();
    if (t < D) {
        int h = t >> 5, k = t & 31;
        float acc = 0.f;
        for (int d = 0; d < D; d++) acc += sIn[d] * W_Q[h*4096 + d*32 + k];
        sQ3[t] = acc;
    } else {
        int c = t - D; int h = c >> 5, k = c & 31;
        float acc = 0.f;
        for (int d = 0; d < D; d++) acc += sMem[d] * W_V[h*4096 + d*32 + k];
        sMV[c] = acc;
    }
    __syncthreads();
    const float scale = 0.17677669529663687f;
    for (int i = t; i < 624; i += 256) {
        int v = i >> 2, h = i & 3;
        const float* qh = sQ3 + h*32;
        float acc = 0.f;
        if (v < 152) {
            const float* ke = KE + v*D + h*32;
            for (int k = 0; k < 32; k++) acc += qh[k] * ke[k];
        } else if (v == 152) {
            const float* ke = KE + p*D + h*32; const float* kp = KP + h*32;
            for (int k = 0; k < 32; k++) acc += qh[k] * (ke[k] + kp[k]);
        } else if (v == 153) {
            const float* ke = KE + EQT*D + h*32; const float* kp = KP + 3*D + h*32;
            for (int k = 0; k < 32; k++) acc += qh[k] * (ke[k] + kp[k]);
        } else if (v == 154) {
            const float* kp = KP + 1*D + h*32;
            for (int k = 0; k < 32; k++) acc += qh[k] * kp[k];
        } else {
            const float* kp = KP + 2*D + h*32;
            for (int k = 0; k < 32; k++) acc += qh[k] * kp[k];
        }
        SC[p*624 + i] = acc * scale;
    }
    if (t < D) {
        float acc = sIn[t];
        for (int c = 0; c < D; c++) acc += sMV[c] * W_O[c*D + t];
        M3B[p*D + t] = (__bf16)acc;
    }
}

// ===== A: attention via tables -> x3 row-major bf16 (1024 blocks x 256) =====
__global__ __launch_bounds__(256, 4) void k_attn(
    const int* __restrict__ p_val, const int* __restrict__ a_tok, const int* __restrict__ b_tok,
    const float* __restrict__ SC, const __bf16* __restrict__ O0, const __bf16* __restrict__ O1,
    const __bf16* __restrict__ O2, const __bf16* __restrict__ O3g, const __bf16* __restrict__ M3B,
    __bf16* __restrict__ X3G)
{
    int tid = threadIdx.x;
    int gbase = blockIdx.x * 64;
    int s = tid >> 2, h = tid & 3;
    int gs = gbase + s;
    int p = p_val[gs], ta = a_tok[gs], tb = b_tok[gs];

    float wloc[4];
    {
        const float* SCp = SC + p*624;
        float sc0 = SCp[608 + h];
        float sc3 = SCp[612 + h];
        float sc1 = SCp[ta*4 + h] + SCp[616 + h];
        float sc2 = SCp[tb*4 + h] + SCp[620 + h];
        float mx = fmaxf(fmaxf(sc0, sc1), fmaxf(sc2, sc3));
        float e0 = expf(sc0-mx), e1 = expf(sc1-mx), e2 = expf(sc2-mx), e3 = expf(sc3-mx);
        float inv = 1.f / (e0 + e1 + e2 + e3);
        wloc[0] = e0*inv; wloc[1] = e1*inv; wloc[2] = e2*inv; wloc[3] = e3*inv;
    }
    float w[16];
    #pragma unroll
    for (int j = 0; j < 4; j++) w[h*4 + j] = wloc[j];
    #pragma unroll
    for (int m = 1; m < 4; m++) {
        int oh = h ^ m;
        #pragma unroll
        for (int j = 0; j < 4; j++) w[oh*4 + j] = __shfl_xor(wloc[j], m);
    }

    const bf16x8* m3v = (const bf16x8*)(M3B + p*128);
    const bf16x8* t0  = (const bf16x8*)(O0 + p*512);
    const bf16x8* t1  = (const bf16x8*)(O1 + ta*512);
    const bf16x8* t2  = (const bf16x8*)(O2 + tb*512);
    const bf16x8* t3  = (const bf16x8*)O3g;
    #pragma unroll
    for (int jj = 0; jj < 4; jj++) {
        int c8 = h*4 + jj;                 // thread covers cols [h*32, h*32+32)
        bf16x8 mv = m3v[c8];
        float v[8];
        #pragma unroll
        for (int e = 0; e < 8; e++) v[e] = (float)mv[e];
        #pragma unroll
        for (int hh = 0; hh < 4; hh++) {
            int o8 = hh*16 + c8;
            bf16x8 e0 = t0[o8], e1 = t1[o8], e2 = t2[o8], e3 = t3[o8];
            float w0 = w[hh*4+0], w1 = w[hh*4+1], w2 = w[hh*4+2], w3 = w[hh*4+3];
            #pragma unroll
            for (int e = 0; e < 8; e++)
                v[e] += w0*(float)e0[e] + w1*(float)e1[e] + w2*(float)e2[e] + w3*(float)e3[e];
        }
        bf16x8 st;
        #pragma unroll
        for (int e = 0; e < 8; e++) st[e] = (__bf16)v[e];
        *(bf16x8*)(X3G + gs*128 + c8*8) = st;
    }
}

// ===== B: MLP + unembed GEMM (512 blocks x 256, 2 tiles/wave, no cross-wave
//          barriers after bias stage; weights streamed L2->reg, shared across
//          both tiles; wave-private LDS panels for H / x'' transpose) =========
__global__ __launch_bounds__(256, 2) void k_mlp(
    const __bf16* __restrict__ X3G,
    const __bf16* __restrict__ W1f, const __bf16* __restrict__ W2f, const __bf16* __restrict__ WUf,
    const float* __restrict__ b1, const float* __restrict__ b2, const float* __restrict__ bun,
    float* __restrict__ out)
{
    __shared__ __align__(16) char smem[38016];   // 4 x 8704 panels + 3200 biases
    float* sB = (float*)(smem + 34816);

    int tid = threadIdx.x;
    int wv = tid >> 6, l = tid & 63, lr = l & 15, quad = l >> 4;
    int tbase = blockIdx.x * 128 + wv * 32;

    for (int i = tid; i < 512; i += 256) sB[i] = b1[i];
    if (tid < 128) sB[512 + tid] = b2[tid];
    if (tid < 160) sB[640 + tid] = bun[tid];

    // A-fragments straight from global (16 B/lane, L2-hot)
    bf16x8 a[2][4];
    #pragma unroll
    for (int t = 0; t < 2; t++)
        #pragma unroll
        for (int kb = 0; kb < 4; kb++)
            a[t][kb] = *(const bf16x8*)(X3G + (tbase + t*16 + lr)*128 + kb*32 + quad*8);

    __syncthreads();   // biases visible; only cross-wave sync in the kernel

    char* sP = smem + wv*8704;     // wave-private: 2 panels of 16 x 136 bf16
    const bf16x8* W1v = (const bf16x8*)W1f;
    const bf16x8* W2v = (const bf16x8*)W2f;
    const bf16x8* WUv = (const bf16x8*)WUf;

    f32x4 acc2[2][8];
    #pragma unroll
    for (int t = 0; t < 2; t++)
        #pragma unroll
        for (int i = 0; i < 8; i++) acc2[t][i] = (f32x4){0.f, 0.f, 0.f, 0.f};

    #pragma unroll
    for (int cc = 0; cc < 8; cc++) {
        #pragma unroll
        for (int nbl = 0; nbl < 4; nbl++) {
            int nbg = cc*4 + nbl;
            float bv = sB[nbg*16 + lr];
            bf16x8 w1[4];
            #pragma unroll
            for (int kb = 0; kb < 4; kb++)
                w1[kb] = W1v[(nbg*4 + kb)*64 + l];
            #pragma unroll
            for (int t = 0; t < 2; t++) {
                f32x4 acc = (f32x4){bv, bv, bv, bv};
                #pragma unroll
                for (int kb = 0; kb < 4; kb++)
                    acc = __builtin_amdgcn_mfma_f32_16x16x32_bf16(a[t][kb], w1[kb], acc, 0, 0, 0);
                char* base = sP + t*4352;
                #pragma unroll
                for (int r = 0; r < 4; r++)
                    *(__bf16*)(base + (((quad*4 + r)*136) + nbl*16 + lr)*2) = (__bf16)fmaxf(acc[r], 0.f);
            }
        }
        #pragma unroll
        for (int kb2 = 0; kb2 < 2; kb2++) {
            bf16x8 h0 = *(const bf16x8*)(sP +        (lr*136 + kb2*32 + quad*8)*2);
            bf16x8 h1 = *(const bf16x8*)(sP + 4352 + (lr*136 + kb2*32 + quad*8)*2);
            #pragma unroll
            for (int nb2 = 0; nb2 < 8; nb2++) {
                bf16x8 w2 = W2v[(nb2*16 + cc*2 + kb2)*64 + l];
                acc2[0][nb2] = __builtin_amdgcn_mfma_f32_16x16x32_bf16(h0, w2, acc2[0][nb2], 0, 0, 0);
                acc2[1][nb2] = __builtin_amdgcn_mfma_f32_16x16x32_bf16(h1, w2, acc2[1][nb2], 0, 0, 0);
            }
        }
    }

    // residual via identity-matrix MFMA
    #pragma unroll
    for (int nb2 = 0; nb2 < 8; nb2++) {
        int kb = nb2 >> 1;
        bf16x8 bi;
        #pragma unroll
        for (int j = 0; j < 8; j++)
            bi[j] = (kb*32 + quad*8 + j == nb2*16 + lr) ? (__bf16)1.0f : (__bf16)0.0f;
        acc2[0][nb2] = __builtin_amdgcn_mfma_f32_16x16x32_bf16(a[0][kb], bi, acc2[0][nb2], 0, 0, 0);
        acc2[1][nb2] = __builtin_amdgcn_mfma_f32_16x16x32_bf16(a[1][kb], bi, acc2[1][nb2], 0, 0, 0);
    }

    // x'' = acc2 + b2 -> both tiles' panels (128 cols each)
    #pragma unroll
    for (int nb2 = 0; nb2 < 8; nb2++) {
        int n = nb2*16 + lr;
        float bv = sB[512 + n];
        #pragma unroll
        for (int t = 0; t < 2; t++) {
            char* base = sP + t*4352;
            #pragma unroll
            for (int r = 0; r < 4; r++) {
                float v = acc2[t][nb2][r] + bv;
                *(__bf16*)(base + (((quad*4 + r)*136) + n)*2) = (__bf16)v;
            }
        }
    }

    bf16x8 au[2][4];
    #pragma unroll
    for (int t = 0; t < 2; t++)
        #pragma unroll
        for (int kb = 0; kb < 4; kb++)
            au[t][kb] = *(const bf16x8*)(sP + t*4352 + (lr*136 + kb*32 + quad*8)*2);

    #pragma unroll
    for (int nt = 0; nt < 10; nt++) {
        int n = nt*16 + lr;
        float bv = (n < 150) ? sB[640 + n] : 0.f;
        bf16x8 wu[4];
        #pragma unroll
        for (int kb = 0; kb < 4; kb++)
            wu[kb] = WUv[(nt*4 + kb)*64 + l];
        #pragma unroll
        for (int t = 0; t < 2; t++) {
            f32x4 acc = (f32x4){bv, bv, bv, bv};
            #pragma unroll
            for (int kb = 0; kb < 4; kb++)
                acc = __builtin_amdgcn_mfma_f32_16x16x32_bf16(au[t][kb], wu[kb], acc, 0, 0, 0);
            if (n < 150) {
                #pragma unroll
                for (int r = 0; r < 4; r++) {
                    int rowg = tbase + t*16 + quad*4 + r;
                    out[rowg*150 + n] = acc[r];
                }
            }
        }
    }
}

// ============================ launcher ======================================
extern "C" void kernel_launch(void* const* d_in, const int* in_sizes, int n_in,
                              void* d_out, int out_size, void* d_ws, size_t ws_size,
                              hipStream_t stream) {
    const int*   p_val = (const int*)d_in[0];
    const int*   a_tok = (const int*)d_in[1];
    const int*   b_tok = (const int*)d_in[2];
    const float* tok   = (const float*)d_in[3];
    const float* pos   = (const float*)d_in[4];
    const float* W_mem = (const float*)d_in[5];
    const float* b_mem = (const float*)d_in[6];
    const float* W_sur = (const float*)d_in[7];
    const float* b_sur = (const float*)d_in[8];
    const float* W_m2r = (const float*)d_in[9];
    const float* b_m2r = (const float*)d_in[10];
    const float* W_Q   = (const float*)d_in[11];
    const float* W_K   = (const float*)d_in[12];
    const float* W_V   = (const float*)d_in[13];
    const float* W_O   = (const float*)d_in[14];
    const float* W1    = (const float*)d_in[15];
    const float* b1    = (const float*)d_in[16];
    const float* W2    = (const float*)d_in[17];
    const float* b2    = (const float*)d_in[18];
    const float* WU    = (const float*)d_in[19];
    const float* bun   = (const float*)d_in[20];
    float* out = (float*)d_out;

    float* ws = (float*)d_ws;
    float* memvec = ws + OFF_MEMVEC;
    float* x3base = ws + OFF_X3BASE;
    float* KE     = ws + OFF_KE;
    float* KP     = ws + OFF_KP;
    float* SC     = ws + OFF_SC;
    __bf16* O0    = (__bf16*)(ws + OFF_O0);
    __bf16* O1    = (__bf16*)(ws + OFF_O1);
    __bf16* O2    = (__bf16*)(ws + OFF_O2);
    __bf16* O3    = (__bf16*)(ws + OFF_O3);
    __bf16* M3B   = (__bf16*)(ws + OFF_M3B);
    __bf16* W1f   = (__bf16*)(ws + OFF_W1F);
    __bf16* W2f   = (__bf16*)(ws + OFF_W2F);
    __bf16* WUf   = (__bf16*)(ws + OFF_WUF);
    __bf16* X3G   = (__bf16*)(ws + OFF_X3G);

    k_P1<<<832, 256, 0, stream>>>(tok, pos, W_mem, b_mem, W_sur, b_sur, W_m2r, b_m2r,
                                  W_K, W_V, W_O, W1, W2, WU,
                                  memvec, x3base, KE, KP, O0, O1, O2, O3, W1f, W2f, WUf);
    k_P2<<<150, 256, 0, stream>>>(memvec, x3base, W_Q, W_V, W_O, KE, KP, SC, M3B);
    k_attn<<<NBATCH/64, 256, 0, stream>>>(p_val, a_tok, b_tok, SC, O0, O1, O2, O3, M3B, X3G);
    k_mlp<<<NBATCH/128, 256, 0, stream>>>(X3G, W1f, W2f, WUf, b1, b2, bun, out);
}

// Round 8
// 193.303 us; speedup vs baseline: 1.4892x; 1.1003x over previous
//
#include <hip/hip_runtime.h>

#define D      128
#define DM     64
#define DMLP   512
#define PMAX   150
#define VOC    152
#define EQT    151
#define NBATCH 65536

typedef __attribute__((ext_vector_type(8))) __bf16 bf16x8;
typedef __attribute__((ext_vector_type(4))) float  f32x4;

__device__ __forceinline__ float silu_f(float x){ return x / (1.0f + expf(-x)); }

// ---- workspace layout (float-slot offsets) ----
#define OFF_MEMVEC 0        // 150*128 f32
#define OFF_X3BASE 19200    // 128 f32
#define OFF_KE     19328    // 152*128 f32
#define OFF_KP     38784    // 4*128 f32
#define OFF_SC     39296    // 150*624 f32
#define OFF_O0     132896   // 150*512 bf16
#define OFF_O1     171296   // 150*512 bf16
#define OFF_O2     209696   // 150*512 bf16
#define OFF_O3     248096   // 512 bf16
#define OFF_M3B    248352   // 150*128 bf16
#define OFF_W1F    257952   // 65536 bf16 frag-packed (chunk-contiguous)
#define OFF_W2F    290720   // 65536 bf16 frag-packed K-major (chunk-contiguous)
#define OFF_WUF    323488   // 20480 bf16
#define OFF_X3G    333728   // 65536*128 bf16 row-major x3

// ===== P1: token-side tables + O-tables + memvec + weight repack (832 blocks x 256)
__global__ void k_P1(const float* __restrict__ tok, const float* __restrict__ pos,
                     const float* __restrict__ W_mem, const float* __restrict__ b_mem,
                     const float* __restrict__ W_sur, const float* __restrict__ b_sur,
                     const float* __restrict__ W_m2r, const float* __restrict__ b_m2r,
                     const float* __restrict__ W_K, const float* __restrict__ W_V,
                     const float* __restrict__ W_O,
                     const float* __restrict__ W1, const float* __restrict__ W2,
                     const float* __restrict__ WU,
                     float* __restrict__ memvec, float* __restrict__ x3base,
                     float* __restrict__ KE, float* __restrict__ KP,
                     __bf16* __restrict__ O0, __bf16* __restrict__ O1,
                     __bf16* __restrict__ O2, __bf16* __restrict__ O3,
                     __bf16* __restrict__ W1f, __bf16* __restrict__ W2f, __bf16* __restrict__ WUf)
{
    int r = blockIdx.x, t = threadIdx.x;
    if (r < 150) {
        int p = r;
        __shared__ float sx0[D], sz[DM], sdiff[D], szu[DM];
        if (t < D) sx0[t] = tok[p*D + t] + pos[t];
        __syncthreads();
        if (t < DM) {
            float acc = b_mem[t];
            for (int d = 0; d < D; d++) acc += sx0[d] * W_mem[d*DM + t];
            sz[t] = silu_f(acc);
        }
        __syncthreads();
        if (t < D) {
            float acc = b_sur[t];
            for (int j = 0; j < DM; j++) acc += sz[j] * W_sur[j*D + t];
            sdiff[t] = sx0[t] - acc;
        }
        __syncthreads();
        if (t < DM) {
            float acc = 0.f;
            for (int d = 0; d < D; d++) acc += sdiff[d] * W_mem[d*DM + t];
            szu[t] = sz[t] + silu_f(acc);
        }
        __syncthreads();
        if (t < D) {
            float acc = b_m2r[t];
            for (int j = 0; j < DM; j++) acc += szu[j] * W_m2r[j*D + t];
            memvec[p*D + t] = acc;
        }
    } else if (r == 150) {
        if (t < D) x3base[t] = tok[EQT*D + t] + pos[3*D + t];
    } else if (r < 307) {
        int idx = r - 151;
        const float* src = (idx < 152) ? (tok + idx*D) : (pos + (idx-152)*D);
        float*       dst = (idx < 152) ? (KE + idx*D)  : (KP + (idx-152)*D);
        __shared__ float s[D];
        if (t < D) s[t] = src[t];
        __syncthreads();
        if (t < D) {
            int h = t >> 5, k = t & 31;
            float acc = 0.f;
            for (int d = 0; d < D; d++) acc += s[d] * W_K[h*4096 + d*32 + k];
            dst[t] = acc;
        }
    } else if (r < 758) {
        int idx = r - 307;
        int tt, v; __bf16* outp;
        if (idx < 150)      { tt = 0; v = idx;       outp = O0 + v*512; }
        else if (idx < 300) { tt = 1; v = idx - 150; outp = O1 + (idx-150)*512; }
        else if (idx < 450) { tt = 2; v = idx - 300; outp = O2 + (idx-300)*512; }
        else                { tt = 3; v = EQT;       outp = O3; }
        __shared__ float sTP[D], sv[D];
        if (t < D) sTP[t] = tok[v*D + t] + pos[tt*D + t];
        __syncthreads();
        if (t < D) {
            int h = t >> 5, k = t & 31;
            float acc = 0.f;
            for (int d = 0; d < D; d++) acc += sTP[d] * W_V[h*4096 + d*32 + k];
            sv[t] = acc;
        }
        __syncthreads();
        #pragma unroll
        for (int i = 0; i < 2; i++) {
            int c = t + i*256;
            int h = c >> 7, m = c & 127;
            float acc = 0.f;
            for (int k = 0; k < 32; k++) acc += sv[h*32 + k] * W_O[h*4096 + k*128 + m];
            outp[c] = (__bf16)acc;
        }
    } else if (r < 790) {
        int f = (r-758)*256 + t;                       // W1 128x512, f=(nbg*4+kb)*64+l
        int l = f & 63, kb = (f>>6) & 3, nb = f >> 8;
        int k0 = kb*32 + (l>>4)*8, n = nb*16 + (l&15);
        #pragma unroll
        for (int j = 0; j < 8; j++) W1f[f*8 + j] = (__bf16)W1[(k0+j)*DMLP + n];
    } else if (r < 822) {
        int f = (r-790)*256 + t;                       // W2 512x128, K-MAJOR: f=(kb*8+nb)*64+l
        int l = f & 63, g = f >> 6;
        int nb = g & 7, kb = g >> 3;
        int k0 = kb*32 + (l>>4)*8, n = nb*16 + (l&15);
        #pragma unroll
        for (int j = 0; j < 8; j++) W2f[f*8 + j] = (__bf16)W2[(k0+j)*D + n];
    } else {
        int f = (r-822)*256 + t;                       // W_un 128x150 (N pad 160), f=(nt*4+kb)*64+l
        int l = f & 63, kb = (f>>6) & 3, nb = f >> 8;
        int k0 = kb*32 + (l>>4)*8, n = nb*16 + (l&15);
        #pragma unroll
        for (int j = 0; j < 8; j++) WUf[f*8 + j] = (__bf16)((n < 150) ? WU[(k0+j)*150 + n] : 0.f);
    }
}

// ===== P2: per-p tables — Q3 (inline), SC score table, M3B (300 blocks x 256)
__global__ void k_P2(const float* __restrict__ memvec, const float* __restrict__ x3base,
                     const float* __restrict__ W_Q, const float* __restrict__ W_V,
                     const float* __restrict__ W_O,
                     const float* __restrict__ KE, const float* __restrict__ KP,
                     float* __restrict__ SC, __bf16* __restrict__ M3B)
{
    int r = blockIdx.x, p = r >> 1, half = r & 1, t = threadIdx.x;
    __shared__ float sMem[D], sIn[D], sQ3[D], sMV[D];
    if (t < D) { float m = memvec[p*D + t]; sMem[t] = m; sIn[t] = m + x3base[t]; }
    __syncthreads();
    if (t < D) {
        int h = t >> 5, k = t & 31;
        float acc = 0.f;
        for (int d = 0; d < D; d++) acc += sIn[d] * W_Q[h*4096 + d*32 + k];
        sQ3[t] = acc;
    } else {
        int c = t - D; int h = c >> 5, k = c & 31;
        float acc = 0.f;
        for (int d = 0; d < D; d++) acc += sMem[d] * W_V[h*4096 + d*32 + k];
        sMV[c] = acc;
    }
    __syncthreads();
    const float scale = 0.17677669529663687f;
    for (int ii = t; ii < 312; ii += 256) {
        int i = half*312 + ii;
        int v = i >> 2, h = i & 3;
        const float4* qh = (const float4*)(sQ3 + h*32);
        float4 s4 = {0.f, 0.f, 0.f, 0.f};
        if (v < 152) {
            const float4* ke = (const float4*)(KE + v*D + h*32);
            #pragma unroll
            for (int k = 0; k < 8; k++) {
                float4 q = qh[k], e = ke[k];
                s4.x += q.x*e.x; s4.y += q.y*e.y; s4.z += q.z*e.z; s4.w += q.w*e.w;
            }
        } else if (v == 152 || v == 153) {
            const float4* ke = (const float4*)(KE + ((v==152)? p : EQT)*D + h*32);
            const float4* kp = (const float4*)(KP + ((v==152)? 0 : 3)*D + h*32);
            #pragma unroll
            for (int k = 0; k < 8; k++) {
                float4 q = qh[k], e = ke[k], pp = kp[k];
                s4.x += q.x*(e.x+pp.x); s4.y += q.y*(e.y+pp.y);
                s4.z += q.z*(e.z+pp.z); s4.w += q.w*(e.w+pp.w);
            }
        } else {
            const float4* kp = (const float4*)(KP + ((v==154)?1:2)*D + h*32);
            #pragma unroll
            for (int k = 0; k < 8; k++) {
                float4 q = qh[k], pp = kp[k];
                s4.x += q.x*pp.x; s4.y += q.y*pp.y; s4.z += q.z*pp.z; s4.w += q.w*pp.w;
            }
        }
        SC[p*624 + i] = (s4.x + s4.y + s4.z + s4.w) * scale;
    }
    if (half == 0 && t < D) {
        float acc = sIn[t];
        for (int c = 0; c < D; c++) acc += sMV[c] * W_O[c*D + t];
        M3B[p*D + t] = (__bf16)acc;
    }
}

// ===== A: attention via tables -> x3 row-major bf16 (1024 blocks x 256) =====
__global__ __launch_bounds__(256, 4) void k_attn(
    const int* __restrict__ p_val, const int* __restrict__ a_tok, const int* __restrict__ b_tok,
    const float* __restrict__ SC, const __bf16* __restrict__ O0, const __bf16* __restrict__ O1,
    const __bf16* __restrict__ O2, const __bf16* __restrict__ O3g, const __bf16* __restrict__ M3B,
    __bf16* __restrict__ X3G)
{
    int tid = threadIdx.x;
    int gbase = blockIdx.x * 64;
    int s = tid >> 2, h = tid & 3;
    int gs = gbase + s;
    int p = p_val[gs], ta = a_tok[gs], tb = b_tok[gs];

    float wloc[4];
    {
        const float* SCp = SC + p*624;
        float sc0 = SCp[608 + h];
        float sc3 = SCp[612 + h];
        float sc1 = SCp[ta*4 + h] + SCp[616 + h];
        float sc2 = SCp[tb*4 + h] + SCp[620 + h];
        float mx = fmaxf(fmaxf(sc0, sc1), fmaxf(sc2, sc3));
        float e0 = expf(sc0-mx), e1 = expf(sc1-mx), e2 = expf(sc2-mx), e3 = expf(sc3-mx);
        float inv = 1.f / (e0 + e1 + e2 + e3);
        wloc[0] = e0*inv; wloc[1] = e1*inv; wloc[2] = e2*inv; wloc[3] = e3*inv;
    }
    float w[16];
    #pragma unroll
    for (int j = 0; j < 4; j++) w[h*4 + j] = wloc[j];
    #pragma unroll
    for (int m = 1; m < 4; m++) {
        int oh = h ^ m;
        #pragma unroll
        for (int j = 0; j < 4; j++) w[oh*4 + j] = __shfl_xor(wloc[j], m);
    }

    const bf16x8* m3v = (const bf16x8*)(M3B + p*128);
    const bf16x8* t0  = (const bf16x8*)(O0 + p*512);
    const bf16x8* t1  = (const bf16x8*)(O1 + ta*512);
    const bf16x8* t2  = (const bf16x8*)(O2 + tb*512);
    const bf16x8* t3  = (const bf16x8*)O3g;
    #pragma unroll
    for (int jj = 0; jj < 4; jj++) {
        int c8 = h*4 + jj;
        bf16x8 mv = m3v[c8];
        float v[8];
        #pragma unroll
        for (int e = 0; e < 8; e++) v[e] = (float)mv[e];
        #pragma unroll
        for (int hh = 0; hh < 4; hh++) {
            int o8 = hh*16 + c8;
            bf16x8 e0 = t0[o8], e1 = t1[o8], e2 = t2[o8], e3 = t3[o8];
            float w0 = w[hh*4+0], w1 = w[hh*4+1], w2 = w[hh*4+2], w3 = w[hh*4+3];
            #pragma unroll
            for (int e = 0; e < 8; e++)
                v[e] += w0*(float)e0[e] + w1*(float)e1[e] + w2*(float)e2[e] + w3*(float)e3[e];
        }
        bf16x8 st;
        #pragma unroll
        for (int e = 0; e < 8; e++) st[e] = (__bf16)v[e];
        *(bf16x8*)(X3G + gs*128 + c8*8) = st;
    }
}

// ===== B: MLP + unembed, LDS-staged weights (1024 blocks x 256, 4 blk/CU) ===
// LDS: [0,8192) W1 chunk | [8192,16384) W2 chunk / WU passes
//      [16384,33792) panels: chunk-phase H (wv*1280), epilogue x'' (wv*4352)
//      [33792,36992) biases
__global__ __launch_bounds__(256, 4) void k_mlpS(
    const __bf16* __restrict__ X3G,
    const __bf16* __restrict__ W1f, const __bf16* __restrict__ W2f, const __bf16* __restrict__ WUf,
    const float* __restrict__ b1, const float* __restrict__ b2, const float* __restrict__ bun,
    float* __restrict__ out)
{
    __shared__ __align__(16) char smem[36992];
    float* sB = (float*)(smem + 33792);

    int tid = threadIdx.x;
    int wv = tid >> 6, l = tid & 63, lr = l & 15, quad = l >> 4;
    int tbase = blockIdx.x * 64 + wv * 16;

    for (int i = tid; i < 512; i += 256) sB[i] = b1[i];
    if (tid < 128) sB[512 + tid] = b2[tid];
    if (tid < 160) sB[640 + tid] = bun[tid];

    // A-fragments from global (L2-hot)
    bf16x8 a[4];
    #pragma unroll
    for (int kb = 0; kb < 4; kb++)
        a[kb] = *(const bf16x8*)(X3G + (tbase + lr)*128 + kb*32 + quad*8);

    const char* gW1 = (const char*)W1f;
    const char* gW2 = (const char*)W2f;
    char* sPanC = smem + 16384 + wv*1280;   // chunk H panel: 16 x 40 bf16

    f32x4 acc2[8];
    #pragma unroll
    for (int i = 0; i < 8; i++) acc2[i] = (f32x4){0.f, 0.f, 0.f, 0.f};

    // prefetch chunk 0 staging data
    float4 v0, v1, v2, v3;
    {
        const float4* g1 = (const float4*)(gW1) + tid*2;
        const float4* g2 = (const float4*)(gW2) + tid*2;
        v0 = g1[0]; v1 = g1[1]; v2 = g2[0]; v3 = g2[1];
    }

    for (int cc = 0; cc < 16; cc++) {
        {   // store staged chunk
            float4* d1 = (float4*)(smem) + tid*2;
            float4* d2 = (float4*)(smem + 8192) + tid*2;
            d1[0] = v0; d1[1] = v1; d2[0] = v2; d2[1] = v3;
        }
        __syncthreads();
        if (cc < 15) {  // issue next chunk's loads — in flight during compute
            const float4* g1 = (const float4*)(gW1 + (cc+1)*8192) + tid*2;
            const float4* g2 = (const float4*)(gW2 + (cc+1)*8192) + tid*2;
            v0 = g1[0]; v1 = g1[1]; v2 = g2[0]; v3 = g2[1];
        }
        // MLP1: 2 col-groups of 16
        #pragma unroll
        for (int nbl = 0; nbl < 2; nbl++) {
            float bv = sB[cc*32 + nbl*16 + lr];
            f32x4 acc = (f32x4){bv, bv, bv, bv};
            #pragma unroll
            for (int kb = 0; kb < 4; kb++) {
                bf16x8 w1 = *(const bf16x8*)(smem + ((nbl*4 + kb)*64 + l)*16);
                acc = __builtin_amdgcn_mfma_f32_16x16x32_bf16(a[kb], w1, acc, 0, 0, 0);
            }
            #pragma unroll
            for (int r = 0; r < 4; r++)
                *(__bf16*)(sPanC + (((quad*4 + r)*40) + nbl*16 + lr)*2) = (__bf16)fmaxf(acc[r], 0.f);
        }
        // MLP2 partial: this chunk's 32-wide K block
        {
            bf16x8 h = *(const bf16x8*)(sPanC + (lr*40 + quad*8)*2);
            #pragma unroll
            for (int nb2 = 0; nb2 < 8; nb2++) {
                bf16x8 w2 = *(const bf16x8*)(smem + 8192 + (nb2*64 + l)*16);
                acc2[nb2] = __builtin_amdgcn_mfma_f32_16x16x32_bf16(h, w2, acc2[nb2], 0, 0, 0);
            }
        }
        __syncthreads();
    }

    // residual via identity-matrix MFMA
    #pragma unroll
    for (int nb2 = 0; nb2 < 8; nb2++) {
        int kb = nb2 >> 1;
        bf16x8 bi;
        #pragma unroll
        for (int j = 0; j < 8; j++)
            bi[j] = (kb*32 + quad*8 + j == nb2*16 + lr) ? (__bf16)1.0f : (__bf16)0.0f;
        acc2[nb2] = __builtin_amdgcn_mfma_f32_16x16x32_bf16(a[kb], bi, acc2[nb2], 0, 0, 0);
    }

    // x'' = acc2 + b2 -> wave-private epilogue panel (16 x 136)
    char* sPanE = smem + 16384 + wv*4352;
    #pragma unroll
    for (int nb2 = 0; nb2 < 8; nb2++) {
        int n = nb2*16 + lr;
        float bv = sB[512 + n];
        #pragma unroll
        for (int r = 0; r < 4; r++) {
            float v = acc2[nb2][r] + bv;
            *(__bf16*)(sPanE + (((quad*4 + r)*136) + n)*2) = (__bf16)v;
        }
    }
    bf16x8 au[4];
    #pragma unroll
    for (int kb = 0; kb < 4; kb++)
        au[kb] = *(const bf16x8*)(sPanE + (lr*136 + kb*32 + quad*8)*2);

    // unembed: WU staged through [0,16384) in 3 passes (nt 0-3, 4-7, 8-9)
    const char* gWU = (const char*)WUf;
    #pragma unroll
    for (int q = 0; q < 3; q++) {
        if (q < 2) {
            const float4* g = (const float4*)(gWU + q*16384) + tid*4;
            float4 u0 = g[0], u1 = g[1], u2 = g[2], u3 = g[3];
            float4* dd = (float4*)(smem) + tid*4;
            dd[0] = u0; dd[1] = u1; dd[2] = u2; dd[3] = u3;
        } else {
            const float4* g = (const float4*)(gWU + 32768) + tid*2;
            float4 u0 = g[0], u1 = g[1];
            float4* dd = (float4*)(smem) + tid*2;
            dd[0] = u0; dd[1] = u1;
        }
        __syncthreads();
        int ntn = (q < 2) ? 4 : 2;
        for (int ntl = 0; ntl < ntn; ntl++) {
            int nt = q*4 + ntl;
            int n = nt*16 + lr;
            float bv = (n < 150) ? sB[640 + n] : 0.f;
            f32x4 acc = (f32x4){bv, bv, bv, bv};
            #pragma unroll
            for (int kb = 0; kb < 4; kb++) {
                bf16x8 wu = *(const bf16x8*)(smem + ((ntl*4 + kb)*64 + l)*16);
                acc = __builtin_amdgcn_mfma_f32_16x16x32_bf16(au[kb], wu, acc, 0, 0, 0);
            }
            if (n < 150) {
                #pragma unroll
                for (int r = 0; r < 4; r++) {
                    int rowg = tbase + quad*4 + r;
                    out[rowg*150 + n] = acc[r];
                }
            }
        }
        if (q < 2) __syncthreads();
    }
}

// ============================ launcher ======================================
extern "C" void kernel_launch(void* const* d_in, const int* in_sizes, int n_in,
                              void* d_out, int out_size, void* d_ws, size_t ws_size,
                              hipStream_t stream) {
    const int*   p_val = (const int*)d_in[0];
    const int*   a_tok = (const int*)d_in[1];
    const int*   b_tok = (const int*)d_in[2];
    const float* tok   = (const float*)d_in[3];
    const float* pos   = (const float*)d_in[4];
    const float* W_mem = (const float*)d_in[5];
    const float* b_mem = (const float*)d_in[6];
    const float* W_sur = (const float*)d_in[7];
    const float* b_sur = (const float*)d_in[8];
    const float* W_m2r = (const float*)d_in[9];
    const float* b_m2r = (const float*)d_in[10];
    const float* W_Q   = (const float*)d_in[11];
    const float* W_K   = (const float*)d_in[12];
    const float* W_V   = (const float*)d_in[13];
    const float* W_O   = (const float*)d_in[14];
    const float* W1    = (const float*)d_in[15];
    const float* b1    = (const float*)d_in[16];
    const float* W2    = (const float*)d_in[17];
    const float* b2    = (const float*)d_in[18];
    const float* WU    = (const float*)d_in[19];
    const float* bun   = (const float*)d_in[20];
    float* out = (float*)d_out;

    float* ws = (float*)d_ws;
    float* memvec = ws + OFF_MEMVEC;
    float* x3base = ws + OFF_X3BASE;
    float* KE     = ws + OFF_KE;
    float* KP     = ws + OFF_KP;
    float* SC     = ws + OFF_SC;
    __bf16* O0    = (__bf16*)(ws + OFF_O0);
    __bf16* O1    = (__bf16*)(ws + OFF_O1);
    __bf16* O2    = (__bf16*)(ws + OFF_O2);
    __bf16* O3    = (__bf16*)(ws + OFF_O3);
    __bf16* M3B   = (__bf16*)(ws + OFF_M3B);
    __bf16* W1f   = (__bf16*)(ws + OFF_W1F);
    __bf16* W2f   = (__bf16*)(ws + OFF_W2F);
    __bf16* WUf   = (__bf16*)(ws + OFF_WUF);
    __bf16* X3G   = (__bf16*)(ws + OFF_X3G);

    k_P1<<<832, 256, 0, stream>>>(tok, pos, W_mem, b_mem, W_sur, b_sur, W_m2r, b_m2r,
                                  W_K, W_V, W_O, W1, W2, WU,
                                  memvec, x3base, KE, KP, O0, O1, O2, O3, W1f, W2f, WUf);
    k_P2<<<300, 256, 0, stream>>>(memvec, x3base, W_Q, W_V, W_O, KE, KP, SC, M3B);
    k_attn<<<NBATCH/64, 256, 0, stream>>>(p_val, a_tok, b_tok, SC, O0, O1, O2, O3, M3B, X3G);
    k_mlpS<<<NBATCH/64, 256, 0, stream>>>(X3G, W1f, W2f, WUf, b1, b2, bun, out);
}